// Round 5
// baseline (255.721 us; speedup 1.0000x reference)
//
#include <hip/hip_runtime.h>
#include <cstddef>

#define NCAPS  10
#define BATCH  256
#define NROUTE 1152
#define CIN    8
#define COUT   16
#define T      1024          // 16 waves = 4 waves/EU (LDS caps 1 block/CU)
#define NB     4             // batch elements per block
#define NWAVE  (T / 64)
#define NBLK   (NCAPS * (BATCH / NB))   // 640 blocks
#define PLANE  (NROUTE * 8)             // u32 (bf16x2) per b-plane = 9216

// bijective 16B-unit swizzle within a b-plane: spreads the 32B-row-stride
// ds_read_b128 pattern to exactly 8 accesses/bank (the minimum).
__device__ __forceinline__ unsigned swzu(unsigned unit) { return unit ^ ((unit >> 3) & 3u); }

// pack two fp32 -> bf16x2 (RNE), low16 = a
__device__ __forceinline__ unsigned pack_bf16(float a, float b) {
    unsigned ua = __float_as_uint(a); ua += 0x7fffu + ((ua >> 16) & 1u);
    unsigned ub = __float_as_uint(b); ub += 0x7fffu + ((ub >> 16) & 1u);
    return (ua >> 16) | (ub & 0xffff0000u);
}
__device__ __forceinline__ float blo(unsigned u) { return __uint_as_float(u << 16); }
__device__ __forceinline__ float bhi(unsigned u) { return __uint_as_float(u & 0xffff0000u); }

// full-wave scalar sum
__device__ __forceinline__ float wave_sum(float v) {
    v += __shfl_xor(v, 1);  v += __shfl_xor(v, 2);  v += __shfl_xor(v, 4);
    v += __shfl_xor(v, 8);  v += __shfl_xor(v, 16); v += __shfl_xor(v, 32);
    return v;
}

// Component-splitting butterfly: reduces s[0..15] over 64 lanes. Lane L (L<16)
// ends with the wave total of component comp(L)=((L&1)<<3)|((L&2)<<1)|((L&4)>>1)|((L&8)>>3).
__device__ __forceinline__ float wave_sum16(float* s, int lane) {
#pragma unroll
    for (int j = 0; j < 8; ++j) {
        float snd = (lane & 1) ? s[j] : s[j + 8];
        float r = __shfl_xor(snd, 1);
        s[j] = ((lane & 1) ? s[j + 8] : s[j]) + r;
    }
#pragma unroll
    for (int j = 0; j < 4; ++j) {
        float snd = (lane & 2) ? s[j] : s[j + 4];
        float r = __shfl_xor(snd, 2);
        s[j] = ((lane & 2) ? s[j + 4] : s[j]) + r;
    }
#pragma unroll
    for (int j = 0; j < 2; ++j) {
        float snd = (lane & 4) ? s[j] : s[j + 2];
        float r = __shfl_xor(snd, 4);
        s[j] = ((lane & 4) ? s[j + 2] : s[j]) + r;
    }
    {
        float snd = (lane & 8) ? s[0] : s[1];
        float r = __shfl_xor(snd, 8);
        s[0] = ((lane & 8) ? s[1] : s[0]) + r;
    }
    s[0] += __shfl_xor(s[0], 16);
    s[0] += __shfl_xor(s[0], 32);
    return s[0];
}

union U4 { uint4 v; unsigned u[4]; };

__global__ __launch_bounds__(T) void caps_routing(const float* __restrict__ x,
                                                  const float* __restrict__ W,
                                                  float* __restrict__ out) {
    __shared__ unsigned prLDS[NB * PLANE];   // 147456 B: priors bf16x2, unit-swizzled
    __shared__ float sred[NWAVE][NB][20];    // [wave][b][comp 0..15, 16=sumExp]
    __shared__ float outLDS[NB][COUT];

    const int tid  = threadIdx.x;
    const int lane = tid & 63;
    const int wv   = tid >> 6;
    const int r2   = 1024 + (tid >> 3);   // leftover route (8 threads/route)
    const int j2   = tid & 7;             // out-pair index within r2

    // XCD-aware swizzle: contiguous widx per XCD -> W working set <=1.2MB, L2-resident
    int g    = blockIdx.x;
    int widx = (g & 7) * (NBLK / 8) + (g >> 3);   // bijective, 640 % 8 == 0
    int c    = widx >> 6;                          // / (BATCH/NB = 64)
    int b0   = (widx & 63) * NB;

    const float* Wc = W + (size_t)c * (NROUTE * CIN * COUT);
    const float* xb = x + (size_t)b0 * (NROUTE * CIN);

    // ---------------- Phase A, route 1: r = tid (full 16-out row) ----------
    {
        const int r = tid;
        float xs[NB][CIN];
#pragma unroll
        for (int b = 0; b < NB; ++b) {
            const float4* xq = (const float4*)(xb + (size_t)b * (NROUTE * CIN) + r * CIN);
            float4 xa = xq[0], xv = xq[1];
            xs[b][0] = xa.x; xs[b][1] = xa.y; xs[b][2] = xa.z; xs[b][3] = xa.w;
            xs[b][4] = xv.x; xs[b][5] = xv.y; xs[b][6] = xv.z; xs[b][7] = xv.w;
        }
        float acc[NB][COUT];
#pragma unroll
        for (int b = 0; b < NB; ++b)
#pragma unroll
            for (int o = 0; o < COUT; ++o) acc[b][o] = 0.f;

        const float4* wp = (const float4*)(Wc + (size_t)r * (CIN * COUT));
#pragma unroll
        for (int i = 0; i < CIN; ++i) {
            float4 w0 = wp[i * 4 + 0], w1 = wp[i * 4 + 1];
            float4 w2 = wp[i * 4 + 2], w3 = wp[i * 4 + 3];
            float wr[16] = {w0.x, w0.y, w0.z, w0.w, w1.x, w1.y, w1.z, w1.w,
                            w2.x, w2.y, w2.z, w2.w, w3.x, w3.y, w3.z, w3.w};
#pragma unroll
            for (int b = 0; b < NB; ++b) {
                const float xi = xs[b][i];
#pragma unroll
                for (int o = 0; o < COUT; ++o) acc[b][o] = fmaf(xi, wr[o], acc[b][o]);
            }
        }
#pragma unroll
        for (int b = 0; b < NB; ++b) {
            U4 qa, qb;
#pragma unroll
            for (int q = 0; q < 4; ++q) {
                qa.u[q] = pack_bf16(acc[b][2 * q], acc[b][2 * q + 1]);
                qb.u[q] = pack_bf16(acc[b][8 + 2 * q], acc[b][8 + 2 * q + 1]);
            }
            unsigned d0 = b * PLANE + swzu(2u * r) * 4u;
            unsigned d1 = b * PLANE + swzu(2u * r + 1u) * 4u;
            *(uint4*)&prLDS[d0] = qa.v;
            *(uint4*)&prLDS[d1] = qb.v;
        }
    }
    // ---------------- Phase A, route 2: r2, outs {2*j2, 2*j2+1} ------------
    {
        float xs2[NB][CIN];
#pragma unroll
        for (int b = 0; b < NB; ++b) {
            const float4* xq = (const float4*)(xb + (size_t)b * (NROUTE * CIN) + r2 * CIN);
            float4 xa = xq[0], xv = xq[1];
            xs2[b][0] = xa.x; xs2[b][1] = xa.y; xs2[b][2] = xa.z; xs2[b][3] = xa.w;
            xs2[b][4] = xv.x; xs2[b][5] = xv.y; xs2[b][6] = xv.z; xs2[b][7] = xv.w;
        }
        float a2[NB][2];
#pragma unroll
        for (int b = 0; b < NB; ++b) { a2[b][0] = 0.f; a2[b][1] = 0.f; }
        const float* wq = Wc + (size_t)r2 * (CIN * COUT) + j2 * 2;
#pragma unroll
        for (int i = 0; i < CIN; ++i) {
            float2 w = *(const float2*)(wq + i * COUT);
#pragma unroll
            for (int b = 0; b < NB; ++b) {
                a2[b][0] = fmaf(xs2[b][i], w.x, a2[b][0]);
                a2[b][1] = fmaf(xs2[b][i], w.y, a2[b][1]);
            }
        }
#pragma unroll
        for (int b = 0; b < NB; ++b) {
            unsigned unit = 2u * (unsigned)r2 + (unsigned)(j2 >> 2);
            unsigned dw = b * PLANE + swzu(unit) * 4u + (j2 & 3);
            prLDS[dw] = pack_bf16(a2[b][0], a2[b][1]);
        }
    }
    __syncthreads();

    // ---------------- Phase B: 3 routing iterations -------------------------
    float lg[NB]  = {0.f, 0.f, 0.f, 0.f};
    float lg2[NB] = {0.f, 0.f, 0.f, 0.f};
    const int comp = ((lane & 1) << 3) | ((lane & 2) << 1) | ((lane & 4) >> 1) | ((lane & 8) >> 3);

    for (int it = 0; it < 3; ++it) {
#pragma unroll
        for (int b = 0; b < NB; ++b) {
            float og[COUT];
            float og2a = 0.f, og2b = 0.f;
            if (it > 0) {
#pragma unroll
                for (int o = 0; o < COUT; ++o) og[o] = outLDS[b][o];
                og2a = outLDS[b][2 * j2];      // LDS-indexed: avoids runtime reg-array index
                og2b = outLDS[b][2 * j2 + 1];
            }
            // route 1: full row from LDS (2x b128, swizzled -> conflict-free)
            unsigned d0 = b * PLANE + swzu(2u * (unsigned)tid) * 4u;
            unsigned d1 = b * PLANE + swzu(2u * (unsigned)tid + 1u) * 4u;
            U4 qa, qb;
            qa.v = *(const uint4*)&prLDS[d0];
            qb.v = *(const uint4*)&prLDS[d1];
            float p[COUT];
#pragma unroll
            for (int q = 0; q < 4; ++q) {
                p[2 * q]     = blo(qa.u[q]);  p[2 * q + 1] = bhi(qa.u[q]);
                p[8 + 2 * q] = blo(qb.u[q]);  p[9 + 2 * q] = bhi(qb.u[q]);
            }
            if (it > 0) {
                float d = 0.f;
#pragma unroll
                for (int o = 0; o < COUT; ++o) d = fmaf(p[o], og[o], d);
                lg[b] += d;
            }
            float e = __expf(lg[b]);   // logits bounded ~|45|, fp32 exp safe
            float se = e;
            float s16[COUT];
#pragma unroll
            for (int o = 0; o < COUT; ++o) s16[o] = e * p[o];

            // route 2: one bf16x2 (outs 2j2,2j2+1); 8 lanes cooperate per route
            unsigned dw = b * PLANE + swzu(2u * (unsigned)r2 + (unsigned)(j2 >> 2)) * 4u + (j2 & 3);
            unsigned u = prLDS[dw];
            float p0 = blo(u), p1 = bhi(u);
            if (it > 0) {
                float d2 = p0 * og2a + p1 * og2b;
                d2 += __shfl_xor(d2, 1); d2 += __shfl_xor(d2, 2); d2 += __shfl_xor(d2, 4);
                lg2[b] += d2;          // identical across the 8-lane group
            }
            float e2 = __expf(lg2[b]);
            se += 0.125f * e2;         // exact: 8 lanes each add 1/8 of exp
#pragma unroll
            for (int o = 0; o < COUT; ++o) {
                float pv = (o & 1) ? p1 : p0;
                s16[o] += ((o >> 1) == j2) ? e2 * pv : 0.f;   // predicated, no runtime index
            }

            float sv  = wave_sum16(s16, lane);
            float sev = wave_sum(se);
            if (lane < 16) sred[wv][b][comp] = sv;
            if (lane == 0) sred[wv][b][16]   = sev;
        }
        __syncthreads();

        if (tid < NB * COUT) {          // 64 threads finish: reduce 16 waves + squash
            const int b = tid >> 4, o = tid & 15;
            float S = 0.f, SE = 0.f;
#pragma unroll
            for (int w = 0; w < NWAVE; ++w) {
                S  += sred[w][b][o];
                SE += sred[w][b][16];
            }
            const float tt = S / SE;
            float pq = tt * tt;
            pq += __shfl_xor(pq, 1); pq += __shfl_xor(pq, 2);
            pq += __shfl_xor(pq, 4); pq += __shfl_xor(pq, 8);   // |s|^2 in 16-lane group
            const float scale = pq / ((1.f + pq) * sqrtf(pq));
            const float val = tt * scale;
            outLDS[b][o] = val;
            if (it == 2) out[((size_t)c * BATCH + b0 + b) * COUT + o] = val;
        }
        __syncthreads();
    }
}

extern "C" void kernel_launch(void* const* d_in, const int* in_sizes, int n_in,
                              void* d_out, int out_size, void* d_ws, size_t ws_size,
                              hipStream_t stream) {
    const float* x = (const float*)d_in[0];
    const float* w = (const float*)d_in[1];
    float* out = (float*)d_out;
    hipLaunchKernelGGL(caps_routing, dim3(NBLK), dim3(T), 0, stream, x, w, out);
}

// Round 6
// 115.499 us; speedup vs baseline: 2.2141x; 2.2141x over previous
//
#include <hip/hip_runtime.h>
#include <cstddef>

#define NCAPS  10
#define BATCH  256
#define NROUTE 1152
#define CIN    8
#define COUT   16
#define T      1024          // 16 waves; LDS (153KB) caps CU at 1 block
#define NB     4             // batch elements per block
#define NWAVE  (T / 64)
#define NBLK   (NCAPS * (BATCH / NB))   // 640 blocks
#define PLANE  (NROUTE * 8)             // u32 (bf16x2) per b-plane = 9216
#define XPLANE (NROUTE * CIN)           // floats per x b-plane = 9216

// bijective 16B-unit swizzle within a b-plane (validated round 5)
__device__ __forceinline__ unsigned swzu(unsigned unit) { return unit ^ ((unit >> 3) & 3u); }

// pack two fp32 -> bf16x2 (RNE), low16 = a
__device__ __forceinline__ unsigned pack_bf16(float a, float b) {
    unsigned ua = __float_as_uint(a); ua += 0x7fffu + ((ua >> 16) & 1u);
    unsigned ub = __float_as_uint(b); ub += 0x7fffu + ((ub >> 16) & 1u);
    return (ua >> 16) | (ub & 0xffff0000u);
}
__device__ __forceinline__ float blo(unsigned u) { return __uint_as_float(u << 16); }
__device__ __forceinline__ float bhi(unsigned u) { return __uint_as_float(u & 0xffff0000u); }

__device__ __forceinline__ float wave_sum(float v) {
    v += __shfl_xor(v, 1);  v += __shfl_xor(v, 2);  v += __shfl_xor(v, 4);
    v += __shfl_xor(v, 8);  v += __shfl_xor(v, 16); v += __shfl_xor(v, 32);
    return v;
}

// Component-splitting butterfly: reduces s[0..15] over 64 lanes. Lane L (L<16)
// ends with the wave total of comp(L)=((L&1)<<3)|((L&2)<<1)|((L&4)>>1)|((L&8)>>3).
__device__ __forceinline__ float wave_sum16(float* s, int lane) {
#pragma unroll
    for (int j = 0; j < 8; ++j) {
        float snd = (lane & 1) ? s[j] : s[j + 8];
        float r = __shfl_xor(snd, 1);
        s[j] = ((lane & 1) ? s[j + 8] : s[j]) + r;
    }
#pragma unroll
    for (int j = 0; j < 4; ++j) {
        float snd = (lane & 2) ? s[j] : s[j + 4];
        float r = __shfl_xor(snd, 2);
        s[j] = ((lane & 2) ? s[j + 4] : s[j]) + r;
    }
#pragma unroll
    for (int j = 0; j < 2; ++j) {
        float snd = (lane & 4) ? s[j] : s[j + 2];
        float r = __shfl_xor(snd, 4);
        s[j] = ((lane & 4) ? s[j + 2] : s[j]) + r;
    }
    {
        float snd = (lane & 8) ? s[0] : s[1];
        float r = __shfl_xor(snd, 8);
        s[0] = ((lane & 8) ? s[1] : s[0]) + r;
    }
    s[0] += __shfl_xor(s[0], 16);
    s[0] += __shfl_xor(s[0], 32);
    return s[0];
}

union U4 { uint4 v; unsigned u[4]; };

__global__ __launch_bounds__(T) void caps_routing(const float* __restrict__ x,
                                                  const float* __restrict__ W,
                                                  float* __restrict__ out) {
    __shared__ unsigned prLDS[NB * PLANE];   // 147456 B: priors bf16x2, unit-swizzled
    __shared__ float sred[NWAVE][NB][20];    // [wave][b][comp 0..15, 16=sumExp]
    __shared__ float VLDS[NB][COUT];         // cumulative output sum (= logit state)

    const int tid  = threadIdx.x;
    const int lane = tid & 63;
    const int wv   = tid >> 6;
    const int r2   = 1024 + (tid >> 3);   // phase-B leftover route (8 threads/route)
    const int j2   = tid & 7;             // out-pair index within r2

    // XCD-aware swizzle: contiguous widx per XCD -> W working set <=1.2MB, L2-resident
    int g    = blockIdx.x;
    int widx = (g & 7) * (NBLK / 8) + (g >> 3);   // bijective, 640 % 8 == 0
    int c    = widx >> 6;                          // / (BATCH/NB = 64)
    int b0   = (widx & 63) * NB;

    const float* Wc = W + (size_t)c * (NROUTE * CIN * COUT);
    const float* xb = x + (size_t)b0 * XPLANE;

    // ---------------- Phase A: (route, out-pair) per thread, 9 passes -------
    // Working set ~50 VGPR (acc[4][2]=8 + xs[4][8]=32 + inflight W): fits the
    // 64-VGPR budget the allocator insists on. W read exactly once per block.
#pragma unroll 1
    for (int pass = 0; pass < (NROUTE * 8) / T; ++pass) {
        const int r = pass * (T / 8) + (tid >> 3);
        const int j = tid & 7;
        float xs[NB][CIN];
#pragma unroll
        for (int b = 0; b < NB; ++b) {
            const float4* xq = (const float4*)(xb + (size_t)b * XPLANE + r * CIN);
            float4 xa = xq[0], xv = xq[1];      // 8-lane broadcast (same addr)
            xs[b][0] = xa.x; xs[b][1] = xa.y; xs[b][2] = xa.z; xs[b][3] = xa.w;
            xs[b][4] = xv.x; xs[b][5] = xv.y; xs[b][6] = xv.z; xs[b][7] = xv.w;
        }
        float2 acc[NB];
#pragma unroll
        for (int b = 0; b < NB; ++b) { acc[b].x = 0.f; acc[b].y = 0.f; }
        const float* wq = Wc + (size_t)r * (CIN * COUT) + j * 2;
#pragma unroll
        for (int i = 0; i < CIN; ++i) {
            float2 w = *(const float2*)(wq + i * COUT);
#pragma unroll
            for (int b = 0; b < NB; ++b) {
                acc[b].x = fmaf(xs[b][i], w.x, acc[b].x);
                acc[b].y = fmaf(xs[b][i], w.y, acc[b].y);
            }
        }
        const unsigned unit = 2u * (unsigned)r + (unsigned)(j >> 2);
        const unsigned base = swzu(unit) * 4u + (unsigned)(j & 3);
#pragma unroll
        for (int b = 0; b < NB; ++b)
            prLDS[b * PLANE + base] = pack_bf16(acc[b].x, acc[b].y);
    }
    __syncthreads();

    // ---------------- Phase B: 3 routing iterations, stateless --------------
    // Linearity: logit_r at iter it = p_r . V where V = sum of previous outputs.
    // V lives in VLDS (updated by squash threads) -> no per-thread logit arrays.
    const int comp = ((lane & 1) << 3) | ((lane & 2) << 1) | ((lane & 4) >> 1) | ((lane & 8) >> 3);

#pragma unroll 1
    for (int it = 0; it < 3; ++it) {
#pragma unroll 1
        for (int b = 0; b < NB; ++b) {
            // main route r = tid: full 16-out row from LDS (2x b128, swizzled)
            const unsigned d0 = b * PLANE + swzu(2u * (unsigned)tid) * 4u;
            const unsigned d1 = b * PLANE + swzu(2u * (unsigned)tid + 1u) * 4u;
            U4 qa, qb;
            qa.v = *(const uint4*)&prLDS[d0];
            qb.v = *(const uint4*)&prLDS[d1];
            float p[COUT];
#pragma unroll
            for (int q = 0; q < 4; ++q) {
                p[2 * q]     = blo(qa.u[q]);  p[2 * q + 1] = bhi(qa.u[q]);
                p[8 + 2 * q] = blo(qb.u[q]);  p[9 + 2 * q] = bhi(qb.u[q]);
            }
            float e;
            if (it > 0) {
                float d = 0.f;
#pragma unroll
                for (int q = 0; q < 4; ++q) {        // stream V 4 floats at a time
                    float4 v4 = *(const float4*)&VLDS[b][4 * q];
                    d = fmaf(p[4 * q + 0], v4.x, d);
                    d = fmaf(p[4 * q + 1], v4.y, d);
                    d = fmaf(p[4 * q + 2], v4.z, d);
                    d = fmaf(p[4 * q + 3], v4.w, d);
                }
                e = __expf(d);
            } else {
                e = 1.f;
            }
            float se = e;
            float s16[COUT];
#pragma unroll
            for (int o = 0; o < COUT; ++o) s16[o] = e * p[o];

            // leftover route r2: one bf16x2 (outs 2j2,2j2+1); 8 lanes cooperate
            {
                const unsigned dw = b * PLANE + swzu(2u * (unsigned)r2 + (unsigned)(j2 >> 2)) * 4u + (j2 & 3);
                const unsigned u = prLDS[dw];
                const float p0 = blo(u), p1 = bhi(u);
                float e2;
                if (it > 0) {
                    float d2 = p0 * VLDS[b][2 * j2] + p1 * VLDS[b][2 * j2 + 1];
                    d2 += __shfl_xor(d2, 1); d2 += __shfl_xor(d2, 2); d2 += __shfl_xor(d2, 4);
                    e2 = __expf(d2);
                } else {
                    e2 = 1.f;
                }
                se += 0.125f * e2;           // exact: 8 lanes each add 1/8 of exp
#pragma unroll
                for (int o = 0; o < COUT; ++o) {
                    const float pv = (o & 1) ? p1 : p0;
                    s16[o] += ((o >> 1) == j2) ? e2 * pv : 0.f;   // predicated
                }
            }

            const float sv  = wave_sum16(s16, lane);
            const float sev = wave_sum(se);
            if (lane < 16) sred[wv][b][comp] = sv;
            if (lane == 0) sred[wv][b][16]   = sev;
        }
        __syncthreads();

        if (tid < NB * COUT) {          // 64 threads: reduce 16 waves + squash
            const int b = tid >> 4, o = tid & 15;
            float S = 0.f, SE = 0.f;
#pragma unroll
            for (int w = 0; w < NWAVE; ++w) {
                S  += sred[w][b][o];
                SE += sred[w][b][16];
            }
            const float tt = S / SE;
            float pq = tt * tt;
            pq += __shfl_xor(pq, 1); pq += __shfl_xor(pq, 2);
            pq += __shfl_xor(pq, 4); pq += __shfl_xor(pq, 8);   // |s|^2 per 16-group
            const float scale = pq / ((1.f + pq) * sqrtf(pq));
            const float val = tt * scale;
            if (it == 2) {
                out[((size_t)c * BATCH + b0 + b) * COUT + o] = val;
            } else {
                VLDS[b][o] = (it == 0) ? val : (VLDS[b][o] + val);  // cumulative V
            }
        }
        __syncthreads();
    }
}

extern "C" void kernel_launch(void* const* d_in, const int* in_sizes, int n_in,
                              void* d_out, int out_size, void* d_ws, size_t ws_size,
                              hipStream_t stream) {
    const float* x = (const float*)d_in[0];
    const float* w = (const float*)d_in[1];
    float* out = (float*)d_out;
    hipLaunchKernelGGL(caps_routing, dim3(NBLK), dim3(T), 0, stream, x, w, out);
}

// Round 7
// 73.412 us; speedup vs baseline: 3.4834x; 1.5733x over previous
//
#include <hip/hip_runtime.h>
#include <cstddef>

#define NCAPS  10
#define BATCH  256
#define NROUTE 1152
#define CIN    8
#define COUT   16
#define T      512           // 8 waves; LDS 75KB -> 2 blocks/CU co-resident
#define NB     2             // batch elements per block
#define NWAVE  (T / 64)
#define NBLK   (NCAPS * (BATCH / NB))   // 1280 blocks = exactly 5 per CU
#define PLANE  (NROUTE * 8)             // u32 (bf16x2) per b-plane = 9216
#define XPLANE (NROUTE * CIN)           // floats per x b-plane = 9216

// bijective 16B-unit swizzle within a b-plane (validated rounds 5-6)
__device__ __forceinline__ unsigned swzu(unsigned unit) { return unit ^ ((unit >> 3) & 3u); }

// pack two fp32 -> bf16x2 (RNE), low16 = a
__device__ __forceinline__ unsigned pack_bf16(float a, float b) {
    unsigned ua = __float_as_uint(a); ua += 0x7fffu + ((ua >> 16) & 1u);
    unsigned ub = __float_as_uint(b); ub += 0x7fffu + ((ub >> 16) & 1u);
    return (ua >> 16) | (ub & 0xffff0000u);
}
__device__ __forceinline__ float blo(unsigned u) { return __uint_as_float(u << 16); }
__device__ __forceinline__ float bhi(unsigned u) { return __uint_as_float(u & 0xffff0000u); }

__device__ __forceinline__ float wave_sum(float v) {
    v += __shfl_xor(v, 1);  v += __shfl_xor(v, 2);  v += __shfl_xor(v, 4);
    v += __shfl_xor(v, 8);  v += __shfl_xor(v, 16); v += __shfl_xor(v, 32);
    return v;
}

// Component-splitting butterfly: reduces s[0..15] over 64 lanes. Lane L (L<16)
// ends with the wave total of comp(L)=((L&1)<<3)|((L&2)<<1)|((L&4)>>1)|((L&8)>>3).
__device__ __forceinline__ float wave_sum16(float* s, int lane) {
#pragma unroll
    for (int j = 0; j < 8; ++j) {
        float snd = (lane & 1) ? s[j] : s[j + 8];
        float r = __shfl_xor(snd, 1);
        s[j] = ((lane & 1) ? s[j + 8] : s[j]) + r;
    }
#pragma unroll
    for (int j = 0; j < 4; ++j) {
        float snd = (lane & 2) ? s[j] : s[j + 4];
        float r = __shfl_xor(snd, 2);
        s[j] = ((lane & 2) ? s[j + 4] : s[j]) + r;
    }
#pragma unroll
    for (int j = 0; j < 2; ++j) {
        float snd = (lane & 4) ? s[j] : s[j + 2];
        float r = __shfl_xor(snd, 4);
        s[j] = ((lane & 4) ? s[j + 2] : s[j]) + r;
    }
    {
        float snd = (lane & 8) ? s[0] : s[1];
        float r = __shfl_xor(snd, 8);
        s[0] = ((lane & 8) ? s[1] : s[0]) + r;
    }
    s[0] += __shfl_xor(s[0], 16);
    s[0] += __shfl_xor(s[0], 32);
    return s[0];
}

union U4 { uint4 v; unsigned u[4]; };

__global__ __launch_bounds__(T) void caps_routing(const float* __restrict__ x,
                                                  const float* __restrict__ W,
                                                  float* __restrict__ out) {
    __shared__ unsigned prLDS[NB * PLANE];          // 73728 B: priors bf16x2, swizzled
    __shared__ float sred[NWAVE][20];               // [wave][comp 0..15, 16=sumExp]
    __shared__ __align__(16) float VLDS[NB][COUT];  // cumulative output (= logit state)

    const int tid  = threadIdx.x;
    const int lane = tid & 63;
    const int wv   = tid >> 6;

    // XCD-aware swizzle: contiguous widx per XCD -> W working set <=1.2MB, L2-resident
    int g    = blockIdx.x;
    int widx = (g & 7) * (NBLK / 8) + (g >> 3);   // bijective, 1280 % 8 == 0
    int c    = widx >> 7;                          // / (BATCH/NB = 128)
    int b0   = (widx & 127) * NB;

    const float* Wc = W + (size_t)c * (NROUTE * CIN * COUT);
    const float* xb = x + (size_t)b0 * XPLANE;

    // ---------------- Phase A: (route, out-pair) per thread, 18 passes ------
    // ~40 live VGPR; W read exactly once per block, coalesced float2.
#pragma unroll 2
    for (int pass = 0; pass < (NROUTE * 8) / T; ++pass) {
        const int r = pass * (T / 8) + (tid >> 3);
        const int j = tid & 7;
        float xs[NB][CIN];
#pragma unroll
        for (int b = 0; b < NB; ++b) {
            const float4* xq = (const float4*)(xb + (size_t)b * XPLANE + r * CIN);
            float4 xa = xq[0], xv = xq[1];      // 8-lane broadcast
            xs[b][0] = xa.x; xs[b][1] = xa.y; xs[b][2] = xa.z; xs[b][3] = xa.w;
            xs[b][4] = xv.x; xs[b][5] = xv.y; xs[b][6] = xv.z; xs[b][7] = xv.w;
        }
        float2 acc[NB];
#pragma unroll
        for (int b = 0; b < NB; ++b) { acc[b].x = 0.f; acc[b].y = 0.f; }
        const float* wq = Wc + (size_t)r * (CIN * COUT) + j * 2;
#pragma unroll
        for (int i = 0; i < CIN; ++i) {
            float2 w = *(const float2*)(wq + i * COUT);
#pragma unroll
            for (int b = 0; b < NB; ++b) {
                acc[b].x = fmaf(xs[b][i], w.x, acc[b].x);
                acc[b].y = fmaf(xs[b][i], w.y, acc[b].y);
            }
        }
        const unsigned base = swzu(2u * (unsigned)r + (unsigned)(j >> 2)) * 4u + (unsigned)(j & 3);
#pragma unroll
        for (int b = 0; b < NB; ++b)
            prLDS[b * PLANE + base] = pack_bf16(acc[b].x, acc[b].y);
    }
    __syncthreads();

    // ---------------- Phase B: b-split (one b per thread), 3 iterations -----
    // Thread owns b = tid>>8, routes r = k*256 + (tid&255) for k=0..3, plus a
    // half-row of leftover route 1024+(tl>>1). Butterflies: 3 total (was 12).
    const int bb = tid >> 8;          // 0..1 (waves 0-3 -> b=0, 4-7 -> b=1)
    const int tl = tid & 255;
    const int h  = tl & 1;            // leftover half
    const int r2 = 1024 + (tl >> 1);  // leftover route
    const int comp = ((lane & 1) << 3) | ((lane & 2) << 1) | ((lane & 4) >> 1) | ((lane & 8) >> 3);

#pragma unroll 1
    for (int it = 0; it < 3; ++it) {
        float s16[COUT];
        float se = 0.f;
#pragma unroll
        for (int o = 0; o < COUT; ++o) s16[o] = 0.f;

        // 4 main routes (independent bodies -> ILP)
#pragma unroll 2
        for (int k = 0; k < 4; ++k) {
            const int r = (k << 8) + tl;
            const unsigned d0 = bb * PLANE + swzu(2u * (unsigned)r) * 4u;
            const unsigned d1 = bb * PLANE + swzu(2u * (unsigned)r + 1u) * 4u;
            U4 qa, qb;
            qa.v = *(const uint4*)&prLDS[d0];
            qb.v = *(const uint4*)&prLDS[d1];
            float p[COUT];
#pragma unroll
            for (int q = 0; q < 4; ++q) {
                p[2 * q]     = blo(qa.u[q]);  p[2 * q + 1] = bhi(qa.u[q]);
                p[8 + 2 * q] = blo(qb.u[q]);  p[9 + 2 * q] = bhi(qb.u[q]);
            }
            float e;
            if (it > 0) {
                float d = 0.f;
#pragma unroll
                for (int q = 0; q < 4; ++q) {
                    float4 v4 = *(const float4*)&VLDS[bb][4 * q];   // broadcast read
                    d = fmaf(p[4 * q + 0], v4.x, d);
                    d = fmaf(p[4 * q + 1], v4.y, d);
                    d = fmaf(p[4 * q + 2], v4.z, d);
                    d = fmaf(p[4 * q + 3], v4.w, d);
                }
                e = __expf(d);   // logit = p . V (linearity), bounded ~|45|
            } else {
                e = 1.f;
            }
            se += e;
#pragma unroll
            for (int o = 0; o < COUT; ++o) s16[o] = fmaf(e, p[o], s16[o]);
        }

        // leftover route: half-row (8 outs) per thread, pair shares the route
        {
            const unsigned dw = bb * PLANE + swzu(2u * (unsigned)r2 + (unsigned)h) * 4u;
            U4 q;
            q.v = *(const uint4*)&prLDS[dw];
            float pl[8];
#pragma unroll
            for (int qq = 0; qq < 4; ++qq) { pl[2 * qq] = blo(q.u[qq]); pl[2 * qq + 1] = bhi(q.u[qq]); }
            float e2;
            if (it > 0) {
                float d2 = 0.f;
#pragma unroll
                for (int j = 0; j < 8; ++j) d2 = fmaf(pl[j], VLDS[bb][h * 8 + j], d2);
                d2 += __shfl_xor(d2, 1);   // combine halves (partner tl^1, same wave)
                e2 = __expf(d2);
            } else {
                e2 = 1.f;
            }
            se += 0.5f * e2;               // 2 lanes each add half of exp -> exact
#pragma unroll
            for (int j = 0; j < 8; ++j) {
                const float add = e2 * pl[j];
                s16[j]     += (h == 0) ? add : 0.f;
                s16[8 + j] += (h == 1) ? add : 0.f;
            }
        }

        const float sv  = wave_sum16(s16, lane);
        const float sev = wave_sum(se);
        if (lane < 16) sred[wv][comp] = sv;
        if (lane == 0) sred[wv][16]   = sev;
        __syncthreads();

        if (tid < NB * COUT) {          // 32 threads: reduce 4 waves/b + squash
            const int b = tid >> 4, o = tid & 15;
            float S = 0.f, SE = 0.f;
#pragma unroll
            for (int w = 0; w < 4; ++w) {
                S  += sred[b * 4 + w][o];
                SE += sred[b * 4 + w][16];
            }
            const float tt = S / SE;
            float pq = tt * tt;
            pq += __shfl_xor(pq, 1); pq += __shfl_xor(pq, 2);
            pq += __shfl_xor(pq, 4); pq += __shfl_xor(pq, 8);   // |s|^2 per 16-group
            const float scale = pq / ((1.f + pq) * sqrtf(pq));
            const float val = tt * scale;
            if (it == 2) {
                out[((size_t)c * BATCH + b0 + b) * COUT + o] = val;
            } else {
                VLDS[b][o] = (it == 0) ? val : (VLDS[b][o] + val);  // cumulative V
            }
        }
        __syncthreads();
    }
}

extern "C" void kernel_launch(void* const* d_in, const int* in_sizes, int n_in,
                              void* d_out, int out_size, void* d_ws, size_t ws_size,
                              hipStream_t stream) {
    const float* x = (const float*)d_in[0];
    const float* w = (const float*)d_in[1];
    float* out = (float*)d_out;
    hipLaunchKernelGGL(caps_routing, dim3(NBLK), dim3(T), 0, stream, x, w, out);
}